// Round 12
// baseline (157.753 us; speedup 1.0000x reference)
//
#include <hip/hip_runtime.h>

typedef __attribute__((ext_vector_type(4))) float f32x4;
typedef __attribute__((ext_vector_type(8))) short short8;

constexpr int NB = 4, NS = 256, NT = 64, ND = 128, NR = 32;
constexpr int WFR = 3 * ND + NR;              // 416
constexpr float SCALE = 0.08838834764831845f; // 1/sqrt(128)

__device__ __forceinline__ unsigned short f2bf(float f) {
  unsigned x = __float_as_uint(f);
  return (unsigned short)((x + 0x7FFFu + ((x >> 16) & 1u)) >> 16);
}
__device__ __forceinline__ float bf2f(unsigned short u) {
  return __uint_as_float((unsigned)u << 16);
}

// ---------------- kPrep: fused kP (blocks 0..115) + kA (116..627) +
// kR (628..1651) + Ht transpose (1652..2675). Block-uniform branches.
__global__ __launch_bounds__(256) void kPrep(
    const float* __restrict__ Wq, const float* __restrict__ Wk,
    const float* __restrict__ Wr, const float* __restrict__ br,
    const float* __restrict__ bq, const float* __restrict__ Wf,
    const float* __restrict__ dH, const float* __restrict__ R,
    const float* __restrict__ H,
    unsigned short* __restrict__ Wqb, unsigned short* __restrict__ Wkb,
    unsigned short* __restrict__ W1b, unsigned short* __restrict__ W2b,
    unsigned short* __restrict__ W3b, unsigned short* __restrict__ Wqrt,
    float* __restrict__ Gbias, float* __restrict__ Ej,
    unsigned short* __restrict__ Rb, unsigned short* __restrict__ Rtb,
    unsigned short* __restrict__ Ht) {
  __shared__ __align__(16) char smem[17408];
  const int blk = blockIdx.x, tid = threadIdx.x;
  if (blk < 116) {
    // ---- kP
    if (blk < 64) {
      const int which = blk >> 4;
      const int idx = ((blk & 15) * 256 + tid) * 4;
      const int e = idx >> 7, d = idx & 127;
      float4 v;
      unsigned short* dst;
      if (which == 0)      { v = *(const float4*)&Wq[idx];            dst = Wqb; }
      else if (which == 1) { v = *(const float4*)&Wk[idx];            dst = Wkb; }
      else if (which == 2) { v = *(const float4*)&Wf[e * WFR + d];        dst = W1b; }
      else                 { v = *(const float4*)&Wf[e * WFR + ND + d];   dst = W2b; }
      dst[idx + 0] = f2bf(v.x); dst[idx + 1] = f2bf(v.y);
      dst[idx + 2] = f2bf(v.z); dst[idx + 3] = f2bf(v.w);
    } else if (blk < 68) {
      const int idx = ((blk - 64) * 256 + tid) * 4;
      const int e = idx >> 5, r = idx & 31;
      float4 v = *(const float4*)&Wf[e * WFR + 2 * ND + r];
      W3b[idx + 0] = f2bf(v.x); W3b[idx + 1] = f2bf(v.y);
      W3b[idx + 2] = f2bf(v.z); W3b[idx + 3] = f2bf(v.w);
    } else {
      const int rr = blk - 68;  // 0..47
      float* Vl = (float*)smem;
      float* gbl = Vl + 128;
      if (tid < 128) {
        float v = 0.f;
        if (rr < 32) v = Wr[tid * 32 + rr];
        else if (rr == 32) v = br[tid];
        Vl[tid] = v;
        gbl[tid] = bq[tid] * v;
      }
      __syncthreads();
      if (tid < 128) {
        float acc = 0.f;
        #pragma unroll 8
        for (int h = 0; h < 128; ++h) acc += Wq[h * 128 + tid] * Vl[h];
        Wqrt[rr * 128 + tid] = f2bf(acc * SCALE);
      }
      if (tid == 0) {
        float g = 0.f;
        for (int h = 0; h < 128; ++h) g += gbl[h];
        Gbias[rr] = g * SCALE;
      }
    }
  } else if (blk < 628) {
    // ---- kA: two (b,j) rows per block
    float* ds = (float*)smem;  // [2][128]
    const int half = tid >> 7, d = tid & 127;
    const int bj = (blk - 116) * 2 + half;
    const float* p = dH + (size_t)bj * NT * ND + d;
    float s = 0.f;
    #pragma unroll 8
    for (int t = 0; t < NT; ++t) s += p[t * ND];
    ds[half * 128 + d] = s;
    __syncthreads();
    const float* w4 = Wf + (size_t)d * WFR + 2 * ND + NR;
    float acc = 0.f;
    #pragma unroll 8
    for (int dd = 0; dd < ND; ++dd) acc += ds[half * 128 + dd] * w4[dd];
    Ej[(size_t)bj * ND + d] = acc;
  } else if (blk < 1652) {
    // ---- kR
    unsigned short* rt = (unsigned short*)smem;  // [256][34]
    const int bi = blk - 628;
    const float* src = R + (size_t)bi * 8192;
    #pragma unroll
    for (int it = 0; it < 8; ++it) {
      const int idx = (tid + it * 256) * 4;
      const float4 v = *(const float4*)&src[idx];
      const unsigned short s0 = f2bf(v.x), s1 = f2bf(v.y);
      const unsigned short s2 = f2bf(v.z), s3 = f2bf(v.w);
      unsigned long long p = (unsigned long long)s0 | ((unsigned long long)s1 << 16)
                           | ((unsigned long long)s2 << 32) | ((unsigned long long)s3 << 48);
      *(unsigned long long*)&Rb[(size_t)bi * 8192 + idx] = p;
      const int j = idx >> 5, r = idx & 31;
      *(unsigned*)&rt[j * 34 + r]     = (unsigned)s0 | ((unsigned)s1 << 16);
      *(unsigned*)&rt[j * 34 + r + 2] = (unsigned)s2 | ((unsigned)s3 << 16);
    }
    __syncthreads();
    #pragma unroll
    for (int it = 0; it < 4; ++it) {
      const int flat = (tid + it * 256) * 8;
      const int r = flat >> 8, j0 = flat & 255;
      short8 o;
      #pragma unroll
      for (int u = 0; u < 8; ++u) o[u] = (short)rt[(j0 + u) * 34 + r];
      *(short8*)&Rtb[(size_t)bi * 8192 + flat] = o;
    }
  } else {
    // ---- Ht: per (b,n), Ht[b][t][n][d] = bf16(H[b][n][t][d])
    const int bn = blk - 1652;
    const int b = bn >> 8, n = bn & 255;
    const float* src = H + (size_t)bn * 8192;
    #pragma unroll
    for (int it = 0; it < 8; ++it) {
      const int idx = (tid + it * 256) * 4;
      const int t = idx >> 7, d = idx & 127;
      const float4 v = *(const float4*)&src[idx];
      unsigned short o0 = f2bf(v.x), o1 = f2bf(v.y), o2 = f2bf(v.z), o3 = f2bf(v.w);
      unsigned long long p = (unsigned long long)o0 | ((unsigned long long)o1 << 16)
                           | ((unsigned long long)o2 << 32) | ((unsigned long long)o3 << 48);
      *(unsigned long long*)&Ht[(((size_t)(b * 64 + t)) * 256 + n) * 128 + d] = p;
    }
  }
}

__device__ __forceinline__ void gemm_tile(const short8 (&afr)[4][4],
    const unsigned short* __restrict__ Wp, int nt, int l15, int l4,
    f32x4 (&acc)[4]) {
  #pragma unroll
  for (int mt = 0; mt < 4; ++mt) acc[mt] = (f32x4){0.f, 0.f, 0.f, 0.f};
  #pragma unroll
  for (int kt = 0; kt < 4; ++kt) {
    short8 bfr = *(const short8*)(Wp + (16 * nt + l15) * 128 + 32 * kt + 8 * l4);
    #pragma unroll
    for (int mt = 0; mt < 4; ++mt)
      acc[mt] = __builtin_amdgcn_mfma_f32_16x16x32_bf16(afr[mt][kt], bfr, acc[mt], 0, 0, 0);
  }
}

__device__ __forceinline__ void gemm_tile2(const short8 (&afr)[2][4],
    const unsigned short* __restrict__ Wp, int nt, int l15, int l4,
    f32x4 (&acc)[2]) {
  #pragma unroll
  for (int mt = 0; mt < 2; ++mt) acc[mt] = (f32x4){0.f, 0.f, 0.f, 0.f};
  #pragma unroll
  for (int kt = 0; kt < 4; ++kt) {
    short8 bfr = *(const short8*)(Wp + (16 * nt + l15) * 128 + 32 * kt + 8 * l4);
    #pragma unroll
    for (int mt = 0; mt < 2; ++mt)
      acc[mt] = __builtin_amdgcn_mfma_f32_16x16x32_bf16(afr[mt][kt], bfr, acc[mt], 0, 0, 0);
  }
}

// ---------------- kB: per (b,n): Apb, BE, G projections; one H read, 1 barrier.
// BE: [b][t][j][e]; Apbb: [b][i][t][e]; G: [b][i][t][48]
__global__ __launch_bounds__(256) void kB(const float* __restrict__ H,
    const unsigned short* __restrict__ W1b, const unsigned short* __restrict__ W2b,
    const unsigned short* __restrict__ Wqrt, const float* __restrict__ Gbias,
    const float* __restrict__ bf, const float* __restrict__ Ej,
    unsigned short* __restrict__ Apbb, unsigned short* __restrict__ BEb,
    unsigned short* __restrict__ Gb) {
  __shared__ unsigned short st[2][64 * 136];  // 34,816 B
  const int bn = blockIdx.x, tid = threadIdx.x;
  const int b = bn >> 8, n = bn & 255;
  const int lane = tid & 63, wv = tid >> 6;
  const int l15 = lane & 15, l4 = lane >> 4;
  // A-fragments of H (bf16 on the fly), resident for all passes
  short8 afr[4][4];
  const float* hb = H + (size_t)bn * (NT * ND);
  #pragma unroll
  for (int mt = 0; mt < 4; ++mt)
    #pragma unroll
    for (int kt = 0; kt < 4; ++kt) {
      const float* p = hb + (16 * mt + l15) * ND + 32 * kt + 8 * l4;
      float4 u0 = *(const float4*)p;
      float4 u1 = *(const float4*)(p + 4);
      short8 f;
      f[0] = (short)f2bf(u0.x); f[1] = (short)f2bf(u0.y);
      f[2] = (short)f2bf(u0.z); f[3] = (short)f2bf(u0.w);
      f[4] = (short)f2bf(u1.x); f[5] = (short)f2bf(u1.y);
      f[6] = (short)f2bf(u1.z); f[7] = (short)f2bf(u1.w);
      afr[mt][kt] = f;
    }
  f32x4 acc[4];
  // passes 0..1 -> LDS buffers (no inter-pass barrier)
  #pragma unroll 1
  for (int pass = 0; pass < 2; ++pass) {
    const unsigned short* W = (pass == 0) ? W1b : W2b;
    unsigned short* buf = st[pass];
    #pragma unroll
    for (int n2 = 0; n2 < 2; ++n2) {
      const int nt = 2 * wv + n2, c = 16 * nt + l15;
      gemm_tile(afr, W, nt, l15, l4, acc);
      const float bias = (pass == 0) ? bf[c] : Ej[(size_t)bn * 128 + c];
      #pragma unroll
      for (int mt = 0; mt < 4; ++mt)
        #pragma unroll
        for (int jr = 0; jr < 4; ++jr)
          buf[(16 * mt + 4 * l4 + jr) * 136 + c] = f2bf(acc[mt][jr] + bias);
    }
  }
  // pass G = H.Wqrt + Gbias (48 cols; waves 0..2) — scalar stores, small
  if (wv < 3) {
    const int nt = wv, c = 16 * nt + l15;
    gemm_tile(afr, Wqrt, nt, l15, l4, acc);
    const float bias = Gbias[c];
    #pragma unroll
    for (int mt = 0; mt < 4; ++mt)
      #pragma unroll
      for (int jr = 0; jr < 4; ++jr) {
        const int tr = 16 * mt + 4 * l4 + jr;
        Gb[(size_t)bn * 3072 + tr * 48 + c] = f2bf(acc[mt][jr] + bias);
      }
  }
  __syncthreads();
  // coalesced stores: 256 B per 16-lane group
  #pragma unroll
  for (int it = 0; it < 4; ++it) {
    const int flat = tid * 8 + it * 2048;
    const int row = flat >> 7, col = flat & 127;  // row = t
    *(short8*)&Apbb[(size_t)bn * 8192 + flat] = *(const short8*)&st[0][row * 136 + col];
    *(short8*)&BEb[((size_t)(b * 64 + row) * 256 + n) * 128 + col] =
        *(const short8*)&st[1][row * 136 + col];
  }
}

// ---------------- kQK: per (b,t): project q,k in-block (LDS), S = SCALE*q.k^T
// Sb: [b][t][i][j]. 512 thr / 8 waves; wave wv owns i-rows [32wv, 32wv+32).
__global__ __launch_bounds__(512) void kQK(const unsigned short* __restrict__ Ht,
    const unsigned short* __restrict__ Wqb, const unsigned short* __restrict__ Wkb,
    const float* __restrict__ bq, const float* __restrict__ bk,
    unsigned short* __restrict__ Sb) {
  __shared__ unsigned short qs[256 * 136];  // 69,632 B (also reused for S staging)
  __shared__ unsigned short ks[256 * 136];  // 69,632 B
  const int bt = blockIdx.x;
  const int tid = threadIdx.x, lane = tid & 63, wv = tid >> 6;
  const int l15 = lane & 15, l4 = lane >> 4;
  // A-fragments from Ht (already bf16, contiguous per (b,t) slice)
  const unsigned short* hsrc = Ht + (size_t)bt * (256 * 128);
  short8 afr[2][4];
  #pragma unroll
  for (int mt = 0; mt < 2; ++mt)
    #pragma unroll
    for (int kt = 0; kt < 4; ++kt) {
      const int n = 32 * wv + 16 * mt + l15;
      afr[mt][kt] = *(const short8*)(hsrc + n * 128 + 32 * kt + 8 * l4);
    }
  // q and k projections -> LDS
  f32x4 acc[2];
  #pragma unroll 1
  for (int pass = 0; pass < 2; ++pass) {
    const unsigned short* W = (pass == 0) ? Wqb : Wkb;
    const float* bp = (pass == 0) ? bq : bk;
    unsigned short* dst = (pass == 0) ? qs : ks;
    #pragma unroll
    for (int nt = 0; nt < 8; ++nt) {
      gemm_tile2(afr, W, nt, l15, l4, acc);
      const int c = 16 * nt + l15;
      const float bias = bp[c];
      #pragma unroll
      for (int mt = 0; mt < 2; ++mt)
        #pragma unroll
        for (int jr = 0; jr < 4; ++jr)
          dst[(32 * wv + 16 * mt + 4 * l4 + jr) * 136 + c] = f2bf(acc[mt][jr] + bias);
    }
  }
  __syncthreads();
  // own q A-fragments from LDS (only this wave wrote/reads these rows)
  short8 qa[2][4];
  #pragma unroll
  for (int mt = 0; mt < 2; ++mt)
    #pragma unroll
    for (int kt = 0; kt < 4; ++kt)
      qa[mt][kt] = *(const short8*)&qs[(32 * wv + 16 * mt + l15) * 136 + 32 * kt + 8 * l4];
  // QK^T in two j-halves; stage into wave-private region of qs, coalesced store
  unsigned short* buf = qs + wv * (32 * 136);
  #pragma unroll 1
  for (int jh = 0; jh < 2; ++jh) {
    f32x4 sacc[2][8];
    #pragma unroll
    for (int mi = 0; mi < 2; ++mi)
      #pragma unroll
      for (int ntj = 0; ntj < 8; ++ntj) sacc[mi][ntj] = (f32x4){0.f, 0.f, 0.f, 0.f};
    #pragma unroll
    for (int kt = 0; kt < 4; ++kt) {
      short8 bb[8];
      #pragma unroll
      for (int ntj = 0; ntj < 8; ++ntj)
        bb[ntj] = *(const short8*)&ks[(16 * (8 * jh + ntj) + l15) * 136 + 32 * kt + 8 * l4];
      #pragma unroll
      for (int mi = 0; mi < 2; ++mi)
        #pragma unroll
        for (int ntj = 0; ntj < 8; ++ntj)
          sacc[mi][ntj] = __builtin_amdgcn_mfma_f32_16x16x32_bf16(qa[mi][kt], bb[ntj], sacc[mi][ntj], 0, 0, 0);
    }
    #pragma unroll
    for (int mi = 0; mi < 2; ++mi)
      #pragma unroll
      for (int ntj = 0; ntj < 8; ++ntj)
        #pragma unroll
        for (int jr = 0; jr < 4; ++jr)
          buf[(16 * mi + 4 * l4 + jr) * 136 + 16 * ntj + l15] =
              f2bf(sacc[mi][ntj][jr] * SCALE);
    #pragma unroll
    for (int it = 0; it < 8; ++it) {
      const int flat = lane * 8 + it * 512;
      const int row = flat >> 7, col = flat & 127;
      *(short8*)&Sb[((size_t)bt * 256 + 32 * wv + row) * 256 + 128 * jh + col] =
          *(const short8*)&buf[row * 136 + col];
    }
  }
}

// ---------------- kSM: per (b,i): scores+softmax+mask+wsum, w->Wbw,
//                  M=w.R, T2=M.W3^T, zacc = Apbb*wsum + T2 (in-place, bf16)
__global__ __launch_bounds__(256) void kSM(
    const unsigned short* __restrict__ Gb, const unsigned short* __restrict__ Rb,
    const unsigned short* __restrict__ Rtb, const unsigned short* __restrict__ Sb,
    const unsigned short* __restrict__ W3b, unsigned short* __restrict__ Apbb,
    unsigned short* __restrict__ Wbw) {
  __shared__ unsigned short wl[64 * 264];
  __shared__ unsigned short Ml[4][16 * 40];
  __shared__ float wred[4][64];
  __shared__ float wsl[64];
  const int bi = blockIdx.x, b = bi >> 8, i = bi & 255;
  const int tid = threadIdx.x, lane = tid & 63, wv = tid >> 6;
  const int l15 = lane & 15, l4 = lane >> 4;
  const f32x4 zz = (f32x4){0.f, 0.f, 0.f, 0.f};

  // stage S tile: wl[t][j] <- Sb[b][t][i][j]  (512 B contiguous per t-row)
  #pragma unroll
  for (int it = 0; it < 8; ++it) {
    const int flat = tid * 8 + it * 2048;
    const int t = flat >> 8, col = flat & 255;
    *(short8*)&wl[t * 264 + col] =
        *(const short8*)&Sb[(((size_t)b * 64 + t) * 256 + i) * 256 + col];
  }

  // P = G . R^T  (K=32)
  short8 ga[4];
  #pragma unroll
  for (int mt = 0; mt < 4; ++mt)
    ga[mt] = *(const short8*)(Gb + ((size_t)bi * 64 + 16 * mt + l15) * 48 + 8 * l4);
  f32x4 acc[4][4];
  #pragma unroll
  for (int nt = 0; nt < 4; ++nt) {
    const int j = 64 * wv + 16 * nt + l15;
    short8 rb = *(const short8*)(Rb + ((size_t)bi * 256 + j) * 32 + 8 * l4);
    #pragma unroll
    for (int mt = 0; mt < 4; ++mt)
      acc[mt][nt] = __builtin_amdgcn_mfma_f32_16x16x32_bf16(ga[mt], rb, zz, 0, 0, 0);
  }
  float qbr[4][4];
  #pragma unroll
  for (int mt = 0; mt < 4; ++mt)
    #pragma unroll
    for (int jr = 0; jr < 4; ++jr)
      qbr[mt][jr] = bf2f(Gb[((size_t)bi * 64 + 16 * mt + 4 * l4 + jr) * 48 + 32]);

  __syncthreads();  // S staged

  // += S + qbr
  #pragma unroll
  for (int mt = 0; mt < 4; ++mt)
    #pragma unroll
    for (int nt = 0; nt < 4; ++nt)
      #pragma unroll
      for (int jr = 0; jr < 4; ++jr)
        acc[mt][nt][jr] += bf2f(wl[(16 * mt + 4 * l4 + jr) * 264 + 64 * wv + 16 * nt + l15])
                         + qbr[mt][jr];

  // softmax over t per column j, diag mask
  #pragma unroll
  for (int nt = 0; nt < 4; ++nt) {
    float mx = -1e30f;
    #pragma unroll
    for (int mt = 0; mt < 4; ++mt)
      #pragma unroll
      for (int jr = 0; jr < 4; ++jr) mx = fmaxf(mx, acc[mt][nt][jr]);
    mx = fmaxf(mx, __shfl_xor(mx, 16));
    mx = fmaxf(mx, __shfl_xor(mx, 32));
    float sm = 0.f;
    #pragma unroll
    for (int mt = 0; mt < 4; ++mt)
      #pragma unroll
      for (int jr = 0; jr < 4; ++jr) {
        const float e = __expf(acc[mt][nt][jr] - mx);
        acc[mt][nt][jr] = e;
        sm += e;
      }
    sm += __shfl_xor(sm, 16);
    sm += __shfl_xor(sm, 32);
    const int j = 64 * wv + 16 * nt + l15;
    const float inv = (j == i) ? 0.f : 1.f / sm;
    #pragma unroll
    for (int mt = 0; mt < 4; ++mt)
      #pragma unroll
      for (int jr = 0; jr < 4; ++jr) acc[mt][nt][jr] *= inv;
  }

  // wsum partials
  float part[4][4];
  #pragma unroll
  for (int mt = 0; mt < 4; ++mt)
    #pragma unroll
    for (int jr = 0; jr < 4; ++jr) {
      float s = 0.f;
      #pragma unroll
      for (int nt = 0; nt < 4; ++nt) s += acc[mt][nt][jr];
      part[mt][jr] = s;
    }
  #pragma unroll
  for (int m = 1; m < 16; m <<= 1)
    #pragma unroll
    for (int mt = 0; mt < 4; ++mt)
      #pragma unroll
      for (int jr = 0; jr < 4; ++jr) part[mt][jr] += __shfl_xor(part[mt][jr], m);
  if (l15 == 0) {
    #pragma unroll
    for (int mt = 0; mt < 4; ++mt)
      #pragma unroll
      for (int jr = 0; jr < 4; ++jr) wred[wv][16 * mt + 4 * l4 + jr] = part[mt][jr];
  }

  // w -> wl (own elements; overwrites staged S values at same addresses)
  #pragma unroll
  for (int mt = 0; mt < 4; ++mt)
    #pragma unroll
    for (int nt = 0; nt < 4; ++nt)
      #pragma unroll
      for (int jr = 0; jr < 4; ++jr)
        wl[(16 * mt + 4 * l4 + jr) * 264 + 64 * wv + 16 * nt + l15] =
            f2bf(acc[mt][nt][jr]);

  __syncthreads();  // w staged + wred complete

  if (tid < 64) wsl[tid] = wred[0][tid] + wred[1][tid] + wred[2][tid] + wred[3][tid];

  // coalesced Wbw store  Wbw[b][t][i][j]
  #pragma unroll
  for (int it = 0; it < 8; ++it) {
    const int flat = tid * 8 + it * 2048;
    const int t = flat >> 8, j = flat & 255;
    *(short8*)&Wbw[(((size_t)(b * 64 + t)) * 256 + i) * 256 + j] =
        *(const short8*)&wl[t * 264 + j];
  }

  // M = w.R : wave wv owns t-rows [16wv, 16wv+16)
  f32x4 mac[2];
  mac[0] = zz; mac[1] = zz;
  #pragma unroll
  for (int kt = 0; kt < 8; ++kt) {
    short8 a = *(const short8*)&wl[(16 * wv + l15) * 264 + 32 * kt + 8 * l4];
    #pragma unroll
    for (int nt = 0; nt < 2; ++nt) {
      short8 bb = *(const short8*)(Rtb + ((size_t)bi * 32 + 16 * nt + l15) * 256 + 32 * kt + 8 * l4);
      mac[nt] = __builtin_amdgcn_mfma_f32_16x16x32_bf16(a, bb, mac[nt], 0, 0, 0);
    }
  }
  #pragma unroll
  for (int nt = 0; nt < 2; ++nt)
    #pragma unroll
    for (int jr = 0; jr < 4; ++jr)
      Ml[wv][(4 * l4 + jr) * 40 + 16 * nt + l15] = f2bf(mac[nt][jr]);
  asm volatile("s_waitcnt lgkmcnt(0)" ::: "memory");
  // T2 = M . W3^T  (K=32)
  short8 a2 = *(const short8*)&Ml[wv][l15 * 40 + 8 * l4];
  f32x4 tac[8];
  #pragma unroll
  for (int nt = 0; nt < 8; ++nt) {
    short8 w3 = *(const short8*)(W3b + (16 * nt + l15) * 32 + 8 * l4);
    tac[nt] = __builtin_amdgcn_mfma_f32_16x16x32_bf16(a2, w3, zz, 0, 0, 0);
  }
  __syncthreads();  // all wl reads (M-step) done

  // stage Apbb tile [64][128] -> wl as [64][136]
  const size_t abase = (size_t)bi * 8192;
  #pragma unroll
  for (int it = 0; it < 4; ++it) {
    const int flat = tid * 8 + it * 2048;
    const int row = flat >> 7, col = flat & 127;
    *(short8*)&wl[row * 136 + col] = *(const short8*)&Apbb[abase + flat];
  }
  __syncthreads();
  // zacc = Apbb * wsum + T2 (in LDS, own elements)
  #pragma unroll
  for (int jr = 0; jr < 4; ++jr) {
    const int t = 16 * wv + 4 * l4 + jr;
    const float ws = wsl[t];
    #pragma unroll
    for (int nt = 0; nt < 8; ++nt) {
      const int e = 16 * nt + l15;
      const int off = t * 136 + e;
      wl[off] = f2bf(bf2f(wl[off]) * ws + tac[nt][jr]);
    }
  }
  __syncthreads();
  #pragma unroll
  for (int it = 0; it < 4; ++it) {
    const int flat = tid * 8 + it * 2048;
    const int row = flat >> 7, col = flat & 127;
    *(short8*)&Apbb[abase + flat] = *(const short8*)&wl[row * 136 + col];
  }
}

// ---------------- kD: per (b,t): out = LN(H + zacc + w.BE)
__global__ __launch_bounds__(512) void kD(const unsigned short* __restrict__ Wb,
    const unsigned short* __restrict__ BEb, const unsigned short* __restrict__ zacc,
    const float* __restrict__ H, const float* __restrict__ gamma,
    const float* __restrict__ beta, float* __restrict__ out) {
  __shared__ unsigned short Bl[128 * 264];
  const int bt = blockIdx.x;
  const int b = bt >> 6, t = bt & 63;
  const int tid = threadIdx.x, lane = tid & 63, wv = tid >> 6;
  const int l15 = lane & 15, l4 = lane >> 4;
  // stage BE[t][j][e] -> Bl[e][j]  (transposed, pad 264); global read contiguous
  {
    const int j = tid >> 1, eh = (tid & 1) * 64;
    const unsigned short* src = BEb + (size_t)bt * (256 * 128) + j * 128 + eh;
    #pragma unroll
    for (int eg = 0; eg < 8; ++eg) {
      short8 v = *(const short8*)(src + 8 * eg);
      #pragma unroll
      for (int u = 0; u < 8; ++u)
        Bl[(eh + 8 * eg + u) * 264 + j] = (unsigned short)v[u];
    }
  }
  __syncthreads();
  f32x4 acc[2][8];
  #pragma unroll
  for (int m2 = 0; m2 < 2; ++m2)
    #pragma unroll
    for (int nt = 0; nt < 8; ++nt) acc[m2][nt] = (f32x4){0.f, 0.f, 0.f, 0.f};
  #pragma unroll
  for (int kt = 0; kt < 8; ++kt) {
    short8 a[2];
    #pragma unroll
    for (int m2 = 0; m2 < 2; ++m2) {
      const int i = 32 * wv + 16 * m2 + l15;
      a[m2] = *(const short8*)(Wb + ((size_t)(b * 64 + t) * 256 + i) * 256 + 32 * kt + 8 * l4);
    }
    #pragma unroll
    for (int nt = 0; nt < 8; ++nt) {
      short8 bb = *(const short8*)(&Bl[(16 * nt + l15) * 264 + 32 * kt + 8 * l4]);
      #pragma unroll
      for (int m2 = 0; m2 < 2; ++m2)
        acc[m2][nt] = __builtin_amdgcn_mfma_f32_16x16x32_bf16(a[m2], bb, acc[m2][nt], 0, 0, 0);
    }
  }
  // epilogue: + zacc + H, LayerNorm over e, store
  float gam[8], bet[8];
  #pragma unroll
  for (int nt = 0; nt < 8; ++nt) {
    const int e = 16 * nt + l15;
    gam[nt] = gamma[e];
    bet[nt] = beta[e];
  }
  #pragma unroll
  for (int m2 = 0; m2 < 2; ++m2)
    #pragma unroll
    for (int jr = 0; jr < 4; ++jr) {
      const int i = 32 * wv + 16 * m2 + 4 * l4 + jr;
      const size_t base = ((size_t)(b * 256 + i) * 64 + t) * 128;
      float x[8];
      float sm = 0.f, sq = 0.f;
      #pragma unroll
      for (int nt = 0; nt < 8; ++nt) {
        const int e = 16 * nt + l15;
        const float v = acc[m2][nt][jr] + bf2f(zacc[base + e]) + H[base + e];
        x[nt] = v;
        sm += v;
        sq += v * v;
      }
      #pragma unroll
      for (int m = 1; m < 16; m <<= 1) {
        sm += __shfl_xor(sm, m);
        sq += __shfl_xor(sq, m);
      }
      const float mu = sm * (1.f / 128.f);
      const float inv = rsqrtf(sq * (1.f / 128.f) - mu * mu + 1e-5f);
      #pragma unroll
      for (int nt = 0; nt < 8; ++nt)
        out[base + 16 * nt + l15] = (x[nt] - mu) * inv * gam[nt] + bet[nt];
    }
}

extern "C" void kernel_launch(void* const* d_in, const int* in_sizes, int n_in,
                              void* d_out, int out_size, void* d_ws, size_t ws_size,
                              hipStream_t stream) {
  (void)in_sizes; (void)n_in; (void)out_size; (void)ws_size;
  const float* H     = (const float*)d_in[0];
  const float* R     = (const float*)d_in[1];
  const float* dH    = (const float*)d_in[2];
  const float* Wq    = (const float*)d_in[3];
  const float* bq    = (const float*)d_in[4];
  const float* Wk    = (const float*)d_in[5];
  const float* bk    = (const float*)d_in[6];
  const float* Wr    = (const float*)d_in[7];
  const float* br    = (const float*)d_in[8];
  const float* Wf    = (const float*)d_in[9];
  const float* bf    = (const float*)d_in[10];
  const float* gamma = (const float*)d_in[11];
  const float* beta  = (const float*)d_in[12];
  float* out = (float*)d_out;
  char* w = (char*)d_ws;

  unsigned short* Wbw  = (unsigned short*)(w + 0);           // 33,554,432
  unsigned short* Sb   = (unsigned short*)(w + 33554432);    // 33,554,432
  unsigned short* Apbb = (unsigned short*)(w + 67108864);    // 16,777,216 (becomes zacc)
  unsigned short* BEb  = (unsigned short*)(w + 83886080);    // 16,777,216
  unsigned short* Gb   = (unsigned short*)(w + 100663296);   //  6,291,456
  unsigned short* Rb   = (unsigned short*)(w + 106954752);   // 16,777,216
  unsigned short* Rtb  = (unsigned short*)(w + 123731968);   // 16,777,216
  float*          Ejb  = (float*)(w + 140509184);            //    524,288
  unsigned short* Wqb  = (unsigned short*)(w + 141033472);   //     32,768
  unsigned short* Wkb  = (unsigned short*)(w + 141066240);
  unsigned short* W1b  = (unsigned short*)(w + 141099008);
  unsigned short* W2b  = (unsigned short*)(w + 141131776);
  unsigned short* W3b  = (unsigned short*)(w + 141164544);   //      8,192
  unsigned short* Wqrt = (unsigned short*)(w + 141172736);   //     12,288
  float*          Gbs  = (float*)(w + 141185024);            //        192
  unsigned short* Ht   = (unsigned short*)(w + 141185280);   // 16,777,216

  kPrep<<<dim3(2676), dim3(256), 0, stream>>>(Wq, Wk, Wr, br, bq, Wf, dH, R, H,
                                              Wqb, Wkb, W1b, W2b, W3b, Wqrt,
                                              Gbs, Ejb, Rb, Rtb, Ht);
  kQK<<<dim3(NB * NT), dim3(512), 0, stream>>>(Ht, Wqb, Wkb, bq, bk, Sb);
  kB<<<dim3(NB * NS), dim3(256), 0, stream>>>(H, W1b, W2b, Wqrt, Gbs,
                                              bf, Ejb, Apbb, BEb, Gb);
  kSM<<<dim3(NB * NS), dim3(256), 0, stream>>>(Gb, Rb, Rtb, Sb, W3b, Apbb, Wbw);
  kD<<<dim3(NB * NT), dim3(512), 0, stream>>>(Wbw, BEb, Apbb, H, gamma, beta, out);
}

// Round 13
// 151.956 us; speedup vs baseline: 1.0381x; 1.0381x over previous
//
#include <hip/hip_runtime.h>

typedef __attribute__((ext_vector_type(4))) float f32x4;
typedef __attribute__((ext_vector_type(8))) short short8;

constexpr int NB = 4, NS = 256, NT = 64, ND = 128, NR = 32;
constexpr int WFR = 3 * ND + NR;              // 416
constexpr float SCALE = 0.08838834764831845f; // 1/sqrt(128)

__device__ __forceinline__ unsigned short f2bf(float f) {
  unsigned x = __float_as_uint(f);
  return (unsigned short)((x + 0x7FFFu + ((x >> 16) & 1u)) >> 16);
}
__device__ __forceinline__ float bf2f(unsigned short u) {
  return __uint_as_float((unsigned)u << 16);
}

// ---------------- kPrep: fused kP (blocks 0..115) + kA (116..627) +
// kR (628..1651). Block-uniform branches.
__global__ __launch_bounds__(256) void kPrep(
    const float* __restrict__ Wq, const float* __restrict__ Wk,
    const float* __restrict__ Wr, const float* __restrict__ br,
    const float* __restrict__ bq, const float* __restrict__ Wf,
    const float* __restrict__ dH, const float* __restrict__ R,
    unsigned short* __restrict__ Wqb, unsigned short* __restrict__ Wkb,
    unsigned short* __restrict__ W1b, unsigned short* __restrict__ W2b,
    unsigned short* __restrict__ W3b, unsigned short* __restrict__ Wqrt,
    float* __restrict__ Gbias, float* __restrict__ Ej,
    unsigned short* __restrict__ Rb, unsigned short* __restrict__ Rtb) {
  __shared__ __align__(16) char smem[17408];
  const int blk = blockIdx.x, tid = threadIdx.x;
  if (blk < 116) {
    // ---- kP
    if (blk < 64) {
      const int which = blk >> 4;
      const int idx = ((blk & 15) * 256 + tid) * 4;
      const int e = idx >> 7, d = idx & 127;
      float4 v;
      unsigned short* dst;
      if (which == 0)      { v = *(const float4*)&Wq[idx];            dst = Wqb; }
      else if (which == 1) { v = *(const float4*)&Wk[idx];            dst = Wkb; }
      else if (which == 2) { v = *(const float4*)&Wf[e * WFR + d];        dst = W1b; }
      else                 { v = *(const float4*)&Wf[e * WFR + ND + d];   dst = W2b; }
      dst[idx + 0] = f2bf(v.x); dst[idx + 1] = f2bf(v.y);
      dst[idx + 2] = f2bf(v.z); dst[idx + 3] = f2bf(v.w);
    } else if (blk < 68) {
      const int idx = ((blk - 64) * 256 + tid) * 4;
      const int e = idx >> 5, r = idx & 31;
      float4 v = *(const float4*)&Wf[e * WFR + 2 * ND + r];
      W3b[idx + 0] = f2bf(v.x); W3b[idx + 1] = f2bf(v.y);
      W3b[idx + 2] = f2bf(v.z); W3b[idx + 3] = f2bf(v.w);
    } else {
      const int rr = blk - 68;  // 0..47
      float* Vl = (float*)smem;
      float* gbl = Vl + 128;
      if (tid < 128) {
        float v = 0.f;
        if (rr < 32) v = Wr[tid * 32 + rr];
        else if (rr == 32) v = br[tid];
        Vl[tid] = v;
        gbl[tid] = bq[tid] * v;
      }
      __syncthreads();
      if (tid < 128) {
        float acc = 0.f;
        #pragma unroll 8
        for (int h = 0; h < 128; ++h) acc += Wq[h * 128 + tid] * Vl[h];
        Wqrt[rr * 128 + tid] = f2bf(acc * SCALE);
      }
      if (tid == 0) {
        float g = 0.f;
        for (int h = 0; h < 128; ++h) g += gbl[h];
        Gbias[rr] = g * SCALE;
      }
    }
  } else if (blk < 628) {
    // ---- kA: two (b,j) rows per block
    float* ds = (float*)smem;  // [2][128]
    const int half = tid >> 7, d = tid & 127;
    const int bj = (blk - 116) * 2 + half;
    const float* p = dH + (size_t)bj * NT * ND + d;
    float s = 0.f;
    #pragma unroll 8
    for (int t = 0; t < NT; ++t) s += p[t * ND];
    ds[half * 128 + d] = s;
    __syncthreads();
    const float* w4 = Wf + (size_t)d * WFR + 2 * ND + NR;
    float acc = 0.f;
    #pragma unroll 8
    for (int dd = 0; dd < ND; ++dd) acc += ds[half * 128 + dd] * w4[dd];
    Ej[(size_t)bj * ND + d] = acc;
  } else {
    // ---- kR
    unsigned short* rt = (unsigned short*)smem;  // [256][34]
    const int bi = blk - 628;
    const float* src = R + (size_t)bi * 8192;
    #pragma unroll
    for (int it = 0; it < 8; ++it) {
      const int idx = (tid + it * 256) * 4;
      const float4 v = *(const float4*)&src[idx];
      const unsigned short s0 = f2bf(v.x), s1 = f2bf(v.y);
      const unsigned short s2 = f2bf(v.z), s3 = f2bf(v.w);
      unsigned long long p = (unsigned long long)s0 | ((unsigned long long)s1 << 16)
                           | ((unsigned long long)s2 << 32) | ((unsigned long long)s3 << 48);
      *(unsigned long long*)&Rb[(size_t)bi * 8192 + idx] = p;
      const int j = idx >> 5, r = idx & 31;
      *(unsigned*)&rt[j * 34 + r]     = (unsigned)s0 | ((unsigned)s1 << 16);
      *(unsigned*)&rt[j * 34 + r + 2] = (unsigned)s2 | ((unsigned)s3 << 16);
    }
    __syncthreads();
    #pragma unroll
    for (int it = 0; it < 4; ++it) {
      const int flat = (tid + it * 256) * 8;
      const int r = flat >> 8, j0 = flat & 255;
      short8 o;
      #pragma unroll
      for (int u = 0; u < 8; ++u) o[u] = (short)rt[(j0 + u) * 34 + r];
      *(short8*)&Rtb[(size_t)bi * 8192 + flat] = o;
    }
  }
}

__device__ __forceinline__ void gemm_tile(const short8 (&afr)[4][4],
    const unsigned short* __restrict__ Wp, int nt, int l15, int l4,
    f32x4 (&acc)[4]) {
  #pragma unroll
  for (int mt = 0; mt < 4; ++mt) acc[mt] = (f32x4){0.f, 0.f, 0.f, 0.f};
  #pragma unroll
  for (int kt = 0; kt < 4; ++kt) {
    short8 bfr = *(const short8*)(Wp + (16 * nt + l15) * 128 + 32 * kt + 8 * l4);
    #pragma unroll
    for (int mt = 0; mt < 4; ++mt)
      acc[mt] = __builtin_amdgcn_mfma_f32_16x16x32_bf16(afr[mt][kt], bfr, acc[mt], 0, 0, 0);
  }
}

__device__ __forceinline__ void gemm_tile2(const short8 (&afr)[2][4],
    const unsigned short* __restrict__ Wp, int nt, int l15, int l4,
    f32x4 (&acc)[2]) {
  #pragma unroll
  for (int mt = 0; mt < 2; ++mt) acc[mt] = (f32x4){0.f, 0.f, 0.f, 0.f};
  #pragma unroll
  for (int kt = 0; kt < 4; ++kt) {
    short8 bfr = *(const short8*)(Wp + (16 * nt + l15) * 128 + 32 * kt + 8 * l4);
    #pragma unroll
    for (int mt = 0; mt < 2; ++mt)
      acc[mt] = __builtin_amdgcn_mfma_f32_16x16x32_bf16(afr[mt][kt], bfr, acc[mt], 0, 0, 0);
  }
}

// ---------------- kB: per (b,n): Apb, BE, G projections + Ht emission.
// BE: [b][t][j][e]; Apbb: [b][i][t][e]; G: [b][i][t][48]; Ht: [b][t][n][d]
__global__ __launch_bounds__(256) void kB(const float* __restrict__ H,
    const unsigned short* __restrict__ W1b, const unsigned short* __restrict__ W2b,
    const unsigned short* __restrict__ Wqrt, const float* __restrict__ Gbias,
    const float* __restrict__ bf, const float* __restrict__ Ej,
    unsigned short* __restrict__ Apbb, unsigned short* __restrict__ BEb,
    unsigned short* __restrict__ Gb, unsigned short* __restrict__ Ht) {
  __shared__ unsigned short st[2][64 * 136];  // 34,816 B
  const int bn = blockIdx.x, tid = threadIdx.x;
  const int b = bn >> 8, n = bn & 255;
  const int lane = tid & 63, wv = tid >> 6;
  const int l15 = lane & 15, l4 = lane >> 4;
  // A-fragments of H (bf16 on the fly); every wave holds the full 64-row tile
  short8 afr[4][4];
  const float* hb = H + (size_t)bn * (NT * ND);
  #pragma unroll
  for (int mt = 0; mt < 4; ++mt)
    #pragma unroll
    for (int kt = 0; kt < 4; ++kt) {
      const float* p = hb + (16 * mt + l15) * ND + 32 * kt + 8 * l4;
      float4 u0 = *(const float4*)p;
      float4 u1 = *(const float4*)(p + 4);
      short8 f;
      f[0] = (short)f2bf(u0.x); f[1] = (short)f2bf(u0.y);
      f[2] = (short)f2bf(u0.z); f[3] = (short)f2bf(u0.w);
      f[4] = (short)f2bf(u1.x); f[5] = (short)f2bf(u1.y);
      f[6] = (short)f2bf(u1.z); f[7] = (short)f2bf(u1.w);
      afr[mt][kt] = f;
    }
  f32x4 acc[4];
  // passes 0..1 -> LDS buffers (no inter-pass barrier)
  #pragma unroll 1
  for (int pass = 0; pass < 2; ++pass) {
    const unsigned short* W = (pass == 0) ? W1b : W2b;
    unsigned short* buf = st[pass];
    #pragma unroll
    for (int n2 = 0; n2 < 2; ++n2) {
      const int nt = 2 * wv + n2, c = 16 * nt + l15;
      gemm_tile(afr, W, nt, l15, l4, acc);
      const float bias = (pass == 0) ? bf[c] : Ej[(size_t)bn * 128 + c];
      #pragma unroll
      for (int mt = 0; mt < 4; ++mt)
        #pragma unroll
        for (int jr = 0; jr < 4; ++jr)
          buf[(16 * mt + 4 * l4 + jr) * 136 + c] = f2bf(acc[mt][jr] + bias);
    }
  }
  // pass G = H.Wqrt + Gbias (48 cols; waves 0..2) — scalar stores, small
  if (wv < 3) {
    const int nt = wv, c = 16 * nt + l15;
    gemm_tile(afr, Wqrt, nt, l15, l4, acc);
    const float bias = Gbias[c];
    #pragma unroll
    for (int mt = 0; mt < 4; ++mt)
      #pragma unroll
      for (int jr = 0; jr < 4; ++jr) {
        const int tr = 16 * mt + 4 * l4 + jr;
        Gb[(size_t)bn * 3072 + tr * 48 + c] = f2bf(acc[mt][jr] + bias);
      }
  }
  __syncthreads();
  // coalesced stores: 256 B per 16-lane group
  #pragma unroll
  for (int it = 0; it < 4; ++it) {
    const int flat = tid * 8 + it * 2048;
    const int row = flat >> 7, col = flat & 127;  // row = t
    *(short8*)&Apbb[(size_t)bn * 8192 + flat] = *(const short8*)&st[0][row * 136 + col];
    *(short8*)&BEb[((size_t)(b * 64 + row) * 256 + n) * 128 + col] =
        *(const short8*)&st[1][row * 136 + col];
  }
  // Ht emission: restage bf16 H tile (wave 0 holds it all) -> coalesced stores
  __syncthreads();
  if (wv == 0) {
    #pragma unroll
    for (int mt = 0; mt < 4; ++mt)
      #pragma unroll
      for (int kt = 0; kt < 4; ++kt)
        *(short8*)&st[0][(16 * mt + l15) * 136 + 32 * kt + 8 * l4] = afr[mt][kt];
  }
  __syncthreads();
  #pragma unroll
  for (int it = 0; it < 4; ++it) {
    const int flat = tid * 8 + it * 2048;
    const int row = flat >> 7, col = flat & 127;  // row = t
    *(short8*)&Ht[((size_t)(b * 64 + row) * 256 + n) * 128 + col] =
        *(const short8*)&st[0][row * 136 + col];
  }
}

// ---------------- kQK: per (b,t): project q,k in-block (LDS), S = SCALE*q.k^T
// Sb: [b][t][i][j]. 512 thr / 8 waves; wave wv owns i-rows [32wv, 32wv+32).
__global__ __launch_bounds__(512) void kQK(const unsigned short* __restrict__ Ht,
    const unsigned short* __restrict__ Wqb, const unsigned short* __restrict__ Wkb,
    const float* __restrict__ bq, const float* __restrict__ bk,
    unsigned short* __restrict__ Sb) {
  __shared__ unsigned short qs[256 * 136];  // 69,632 B (also reused for S staging)
  __shared__ unsigned short ks[256 * 136];  // 69,632 B
  const int bt = blockIdx.x;
  const int tid = threadIdx.x, lane = tid & 63, wv = tid >> 6;
  const int l15 = lane & 15, l4 = lane >> 4;
  // A-fragments from Ht (already bf16, contiguous per (b,t) slice)
  const unsigned short* hsrc = Ht + (size_t)bt * (256 * 128);
  short8 afr[2][4];
  #pragma unroll
  for (int mt = 0; mt < 2; ++mt)
    #pragma unroll
    for (int kt = 0; kt < 4; ++kt) {
      const int n = 32 * wv + 16 * mt + l15;
      afr[mt][kt] = *(const short8*)(hsrc + n * 128 + 32 * kt + 8 * l4);
    }
  // q and k projections -> LDS
  f32x4 acc[2];
  #pragma unroll 1
  for (int pass = 0; pass < 2; ++pass) {
    const unsigned short* W = (pass == 0) ? Wqb : Wkb;
    const float* bp = (pass == 0) ? bq : bk;
    unsigned short* dst = (pass == 0) ? qs : ks;
    #pragma unroll
    for (int nt = 0; nt < 8; ++nt) {
      gemm_tile2(afr, W, nt, l15, l4, acc);
      const int c = 16 * nt + l15;
      const float bias = bp[c];
      #pragma unroll
      for (int mt = 0; mt < 2; ++mt)
        #pragma unroll
        for (int jr = 0; jr < 4; ++jr)
          dst[(32 * wv + 16 * mt + 4 * l4 + jr) * 136 + c] = f2bf(acc[mt][jr] + bias);
    }
  }
  __syncthreads();
  // own q A-fragments from LDS (only this wave wrote/reads these rows)
  short8 qa[2][4];
  #pragma unroll
  for (int mt = 0; mt < 2; ++mt)
    #pragma unroll
    for (int kt = 0; kt < 4; ++kt)
      qa[mt][kt] = *(const short8*)&qs[(32 * wv + 16 * mt + l15) * 136 + 32 * kt + 8 * l4];
  // QK^T in two j-halves; stage into wave-private region of qs, coalesced store
  unsigned short* buf = qs + wv * (32 * 136);
  #pragma unroll 1
  for (int jh = 0; jh < 2; ++jh) {
    f32x4 sacc[2][8];
    #pragma unroll
    for (int mi = 0; mi < 2; ++mi)
      #pragma unroll
      for (int ntj = 0; ntj < 8; ++ntj) sacc[mi][ntj] = (f32x4){0.f, 0.f, 0.f, 0.f};
    #pragma unroll
    for (int kt = 0; kt < 4; ++kt) {
      short8 bb[8];
      #pragma unroll
      for (int ntj = 0; ntj < 8; ++ntj)
        bb[ntj] = *(const short8*)&ks[(16 * (8 * jh + ntj) + l15) * 136 + 32 * kt + 8 * l4];
      #pragma unroll
      for (int mi = 0; mi < 2; ++mi)
        #pragma unroll
        for (int ntj = 0; ntj < 8; ++ntj)
          sacc[mi][ntj] = __builtin_amdgcn_mfma_f32_16x16x32_bf16(qa[mi][kt], bb[ntj], sacc[mi][ntj], 0, 0, 0);
    }
    #pragma unroll
    for (int mi = 0; mi < 2; ++mi)
      #pragma unroll
      for (int ntj = 0; ntj < 8; ++ntj)
        #pragma unroll
        for (int jr = 0; jr < 4; ++jr)
          buf[(16 * mi + 4 * l4 + jr) * 136 + 16 * ntj + l15] =
              f2bf(sacc[mi][ntj][jr] * SCALE);
    #pragma unroll
    for (int it = 0; it < 8; ++it) {
      const int flat = lane * 8 + it * 512;
      const int row = flat >> 7, col = flat & 127;
      *(short8*)&Sb[((size_t)bt * 256 + 32 * wv + row) * 256 + 128 * jh + col] =
          *(const short8*)&buf[row * 136 + col];
    }
  }
}

// ---------------- kSM: per (b,i): scores+softmax+mask+wsum, w->Wbw,
//                  M=w.R, T2=M.W3^T, zacc = Apbb*wsum + T2 (in-place, bf16)
__global__ __launch_bounds__(256) void kSM(
    const unsigned short* __restrict__ Gb, const unsigned short* __restrict__ Rb,
    const unsigned short* __restrict__ Rtb, const unsigned short* __restrict__ Sb,
    const unsigned short* __restrict__ W3b, unsigned short* __restrict__ Apbb,
    unsigned short* __restrict__ Wbw) {
  __shared__ unsigned short wl[64 * 264];
  __shared__ unsigned short Ml[4][16 * 40];
  __shared__ float wred[4][64];
  __shared__ float wsl[64];
  const int bi = blockIdx.x, b = bi >> 8, i = bi & 255;
  const int tid = threadIdx.x, lane = tid & 63, wv = tid >> 6;
  const int l15 = lane & 15, l4 = lane >> 4;
  const f32x4 zz = (f32x4){0.f, 0.f, 0.f, 0.f};

  // stage S tile: wl[t][j] <- Sb[b][t][i][j]  (512 B contiguous per t-row)
  #pragma unroll
  for (int it = 0; it < 8; ++it) {
    const int flat = tid * 8 + it * 2048;
    const int t = flat >> 8, col = flat & 255;
    *(short8*)&wl[t * 264 + col] =
        *(const short8*)&Sb[(((size_t)b * 64 + t) * 256 + i) * 256 + col];
  }

  // P = G . R^T  (K=32)
  short8 ga[4];
  #pragma unroll
  for (int mt = 0; mt < 4; ++mt)
    ga[mt] = *(const short8*)(Gb + ((size_t)bi * 64 + 16 * mt + l15) * 48 + 8 * l4);
  f32x4 acc[4][4];
  #pragma unroll
  for (int nt = 0; nt < 4; ++nt) {
    const int j = 64 * wv + 16 * nt + l15;
    short8 rb = *(const short8*)(Rb + ((size_t)bi * 256 + j) * 32 + 8 * l4);
    #pragma unroll
    for (int mt = 0; mt < 4; ++mt)
      acc[mt][nt] = __builtin_amdgcn_mfma_f32_16x16x32_bf16(ga[mt], rb, zz, 0, 0, 0);
  }
  float qbr[4][4];
  #pragma unroll
  for (int mt = 0; mt < 4; ++mt)
    #pragma unroll
    for (int jr = 0; jr < 4; ++jr)
      qbr[mt][jr] = bf2f(Gb[((size_t)bi * 64 + 16 * mt + 4 * l4 + jr) * 48 + 32]);

  __syncthreads();  // S staged

  // += S + qbr
  #pragma unroll
  for (int mt = 0; mt < 4; ++mt)
    #pragma unroll
    for (int nt = 0; nt < 4; ++nt)
      #pragma unroll
      for (int jr = 0; jr < 4; ++jr)
        acc[mt][nt][jr] += bf2f(wl[(16 * mt + 4 * l4 + jr) * 264 + 64 * wv + 16 * nt + l15])
                         + qbr[mt][jr];

  // softmax over t per column j, diag mask
  #pragma unroll
  for (int nt = 0; nt < 4; ++nt) {
    float mx = -1e30f;
    #pragma unroll
    for (int mt = 0; mt < 4; ++mt)
      #pragma unroll
      for (int jr = 0; jr < 4; ++jr) mx = fmaxf(mx, acc[mt][nt][jr]);
    mx = fmaxf(mx, __shfl_xor(mx, 16));
    mx = fmaxf(mx, __shfl_xor(mx, 32));
    float sm = 0.f;
    #pragma unroll
    for (int mt = 0; mt < 4; ++mt)
      #pragma unroll
      for (int jr = 0; jr < 4; ++jr) {
        const float e = __expf(acc[mt][nt][jr] - mx);
        acc[mt][nt][jr] = e;
        sm += e;
      }
    sm += __shfl_xor(sm, 16);
    sm += __shfl_xor(sm, 32);
    const int j = 64 * wv + 16 * nt + l15;
    const float inv = (j == i) ? 0.f : 1.f / sm;
    #pragma unroll
    for (int mt = 0; mt < 4; ++mt)
      #pragma unroll
      for (int jr = 0; jr < 4; ++jr) acc[mt][nt][jr] *= inv;
  }

  // wsum partials
  float part[4][4];
  #pragma unroll
  for (int mt = 0; mt < 4; ++mt)
    #pragma unroll
    for (int jr = 0; jr < 4; ++jr) {
      float s = 0.f;
      #pragma unroll
      for (int nt = 0; nt < 4; ++nt) s += acc[mt][nt][jr];
      part[mt][jr] = s;
    }
  #pragma unroll
  for (int m = 1; m < 16; m <<= 1)
    #pragma unroll
    for (int mt = 0; mt < 4; ++mt)
      #pragma unroll
      for (int jr = 0; jr < 4; ++jr) part[mt][jr] += __shfl_xor(part[mt][jr], m);
  if (l15 == 0) {
    #pragma unroll
    for (int mt = 0; mt < 4; ++mt)
      #pragma unroll
      for (int jr = 0; jr < 4; ++jr) wred[wv][16 * mt + 4 * l4 + jr] = part[mt][jr];
  }

  // w -> wl (own elements; overwrites staged S values at same addresses)
  #pragma unroll
  for (int mt = 0; mt < 4; ++mt)
    #pragma unroll
    for (int nt = 0; nt < 4; ++nt)
      #pragma unroll
      for (int jr = 0; jr < 4; ++jr)
        wl[(16 * mt + 4 * l4 + jr) * 264 + 64 * wv + 16 * nt + l15] =
            f2bf(acc[mt][nt][jr]);

  __syncthreads();  // w staged + wred complete

  if (tid < 64) wsl[tid] = wred[0][tid] + wred[1][tid] + wred[2][tid] + wred[3][tid];

  // coalesced Wbw store  Wbw[b][t][i][j]
  #pragma unroll
  for (int it = 0; it < 8; ++it) {
    const int flat = tid * 8 + it * 2048;
    const int t = flat >> 8, j = flat & 255;
    *(short8*)&Wbw[(((size_t)(b * 64 + t)) * 256 + i) * 256 + j] =
        *(const short8*)&wl[t * 264 + j];
  }

  // M = w.R : wave wv owns t-rows [16wv, 16wv+16)
  f32x4 mac[2];
  mac[0] = zz; mac[1] = zz;
  #pragma unroll
  for (int kt = 0; kt < 8; ++kt) {
    short8 a = *(const short8*)&wl[(16 * wv + l15) * 264 + 32 * kt + 8 * l4];
    #pragma unroll
    for (int nt = 0; nt < 2; ++nt) {
      short8 bb = *(const short8*)(Rtb + ((size_t)bi * 32 + 16 * nt + l15) * 256 + 32 * kt + 8 * l4);
      mac[nt] = __builtin_amdgcn_mfma_f32_16x16x32_bf16(a, bb, mac[nt], 0, 0, 0);
    }
  }
  #pragma unroll
  for (int nt = 0; nt < 2; ++nt)
    #pragma unroll
    for (int jr = 0; jr < 4; ++jr)
      Ml[wv][(4 * l4 + jr) * 40 + 16 * nt + l15] = f2bf(mac[nt][jr]);
  asm volatile("s_waitcnt lgkmcnt(0)" ::: "memory");
  // T2 = M . W3^T  (K=32)
  short8 a2 = *(const short8*)&Ml[wv][l15 * 40 + 8 * l4];
  f32x4 tac[8];
  #pragma unroll
  for (int nt = 0; nt < 8; ++nt) {
    short8 w3 = *(const short8*)(W3b + (16 * nt + l15) * 32 + 8 * l4);
    tac[nt] = __builtin_amdgcn_mfma_f32_16x16x32_bf16(a2, w3, zz, 0, 0, 0);
  }
  __syncthreads();  // all wl reads (M-step) done

  // stage Apbb tile [64][128] -> wl as [64][136]
  const size_t abase = (size_t)bi * 8192;
  #pragma unroll
  for (int it = 0; it < 4; ++it) {
    const int flat = tid * 8 + it * 2048;
    const int row = flat >> 7, col = flat & 127;
    *(short8*)&wl[row * 136 + col] = *(const short8*)&Apbb[abase + flat];
  }
  __syncthreads();
  // zacc = Apbb * wsum + T2 (in LDS, own elements)
  #pragma unroll
  for (int jr = 0; jr < 4; ++jr) {
    const int t = 16 * wv + 4 * l4 + jr;
    const float ws = wsl[t];
    #pragma unroll
    for (int nt = 0; nt < 8; ++nt) {
      const int e = 16 * nt + l15;
      const int off = t * 136 + e;
      wl[off] = f2bf(bf2f(wl[off]) * ws + tac[nt][jr]);
    }
  }
  __syncthreads();
  #pragma unroll
  for (int it = 0; it < 4; ++it) {
    const int flat = tid * 8 + it * 2048;
    const int row = flat >> 7, col = flat & 127;
    *(short8*)&Apbb[abase + flat] = *(const short8*)&wl[row * 136 + col];
  }
}

// ---------------- kD: per (b,t): out = LN(H + zacc + w.BE)
__global__ __launch_bounds__(512) void kD(const unsigned short* __restrict__ Wb,
    const unsigned short* __restrict__ BEb, const unsigned short* __restrict__ zacc,
    const float* __restrict__ H, const float* __restrict__ gamma,
    const float* __restrict__ beta, float* __restrict__ out) {
  __shared__ unsigned short Bl[128 * 264];
  const int bt = blockIdx.x;
  const int b = bt >> 6, t = bt & 63;
  const int tid = threadIdx.x, lane = tid & 63, wv = tid >> 6;
  const int l15 = lane & 15, l4 = lane >> 4;
  // stage BE[t][j][e] -> Bl[e][j]  (transposed, pad 264); global read contiguous
  {
    const int j = tid >> 1, eh = (tid & 1) * 64;
    const unsigned short* src = BEb + (size_t)bt * (256 * 128) + j * 128 + eh;
    #pragma unroll
    for (int eg = 0; eg < 8; ++eg) {
      short8 v = *(const short8*)(src + 8 * eg);
      #pragma unroll
      for (int u = 0; u < 8; ++u)
        Bl[(eh + 8 * eg + u) * 264 + j] = (unsigned short)v[u];
    }
  }
  __syncthreads();
  f32x4 acc[2][8];
  #pragma unroll
  for (int m2 = 0; m2 < 2; ++m2)
    #pragma unroll
    for (int nt = 0; nt < 8; ++nt) acc[m2][nt] = (f32x4){0.f, 0.f, 0.f, 0.f};
  #pragma unroll
  for (int kt = 0; kt < 8; ++kt) {
    short8 a[2];
    #pragma unroll
    for (int m2 = 0; m2 < 2; ++m2) {
      const int i = 32 * wv + 16 * m2 + l15;
      a[m2] = *(const short8*)(Wb + ((size_t)(b * 64 + t) * 256 + i) * 256 + 32 * kt + 8 * l4);
    }
    #pragma unroll
    for (int nt = 0; nt < 8; ++nt) {
      short8 bb = *(const short8*)(&Bl[(16 * nt + l15) * 264 + 32 * kt + 8 * l4]);
      #pragma unroll
      for (int m2 = 0; m2 < 2; ++m2)
        acc[m2][nt] = __builtin_amdgcn_mfma_f32_16x16x32_bf16(a[m2], bb, acc[m2][nt], 0, 0, 0);
    }
  }
  // epilogue: + zacc + H, LayerNorm over e, store
  float gam[8], bet[8];
  #pragma unroll
  for (int nt = 0; nt < 8; ++nt) {
    const int e = 16 * nt + l15;
    gam[nt] = gamma[e];
    bet[nt] = beta[e];
  }
  #pragma unroll
  for (int m2 = 0; m2 < 2; ++m2)
    #pragma unroll
    for (int jr = 0; jr < 4; ++jr) {
      const int i = 32 * wv + 16 * m2 + 4 * l4 + jr;
      const size_t base = ((size_t)(b * 256 + i) * 64 + t) * 128;
      float x[8];
      float sm = 0.f, sq = 0.f;
      #pragma unroll
      for (int nt = 0; nt < 8; ++nt) {
        const int e = 16 * nt + l15;
        const float v = acc[m2][nt][jr] + bf2f(zacc[base + e]) + H[base + e];
        x[nt] = v;
        sm += v;
        sq += v * v;
      }
      #pragma unroll
      for (int m = 1; m < 16; m <<= 1) {
        sm += __shfl_xor(sm, m);
        sq += __shfl_xor(sq, m);
      }
      const float mu = sm * (1.f / 128.f);
      const float inv = rsqrtf(sq * (1.f / 128.f) - mu * mu + 1e-5f);
      #pragma unroll
      for (int nt = 0; nt < 8; ++nt)
        out[base + 16 * nt + l15] = (x[nt] - mu) * inv * gam[nt] + bet[nt];
    }
}

extern "C" void kernel_launch(void* const* d_in, const int* in_sizes, int n_in,
                              void* d_out, int out_size, void* d_ws, size_t ws_size,
                              hipStream_t stream) {
  (void)in_sizes; (void)n_in; (void)out_size; (void)ws_size;
  const float* H     = (const float*)d_in[0];
  const float* R     = (const float*)d_in[1];
  const float* dH    = (const float*)d_in[2];
  const float* Wq    = (const float*)d_in[3];
  const float* bq    = (const float*)d_in[4];
  const float* Wk    = (const float*)d_in[5];
  const float* bk    = (const float*)d_in[6];
  const float* Wr    = (const float*)d_in[7];
  const float* br    = (const float*)d_in[8];
  const float* Wf    = (const float*)d_in[9];
  const float* bf    = (const float*)d_in[10];
  const float* gamma = (const float*)d_in[11];
  const float* beta  = (const float*)d_in[12];
  float* out = (float*)d_out;
  char* w = (char*)d_ws;

  unsigned short* Wbw  = (unsigned short*)(w + 0);           // 33,554,432
  unsigned short* Sb   = (unsigned short*)(w + 33554432);    // 33,554,432
  unsigned short* Apbb = (unsigned short*)(w + 67108864);    // 16,777,216 (becomes zacc)
  unsigned short* BEb  = (unsigned short*)(w + 83886080);    // 16,777,216
  unsigned short* Gb   = (unsigned short*)(w + 100663296);   //  6,291,456
  unsigned short* Rb   = (unsigned short*)(w + 106954752);   // 16,777,216
  unsigned short* Rtb  = (unsigned short*)(w + 123731968);   // 16,777,216
  float*          Ejb  = (float*)(w + 140509184);            //    524,288
  unsigned short* Wqb  = (unsigned short*)(w + 141033472);   //     32,768
  unsigned short* Wkb  = (unsigned short*)(w + 141066240);
  unsigned short* W1b  = (unsigned short*)(w + 141099008);
  unsigned short* W2b  = (unsigned short*)(w + 141131776);
  unsigned short* W3b  = (unsigned short*)(w + 141164544);   //      8,192
  unsigned short* Wqrt = (unsigned short*)(w + 141172736);   //     12,288
  float*          Gbs  = (float*)(w + 141185024);            //        192
  unsigned short* Ht   = (unsigned short*)(w + 141185280);   // 16,777,216

  kPrep<<<dim3(1652), dim3(256), 0, stream>>>(Wq, Wk, Wr, br, bq, Wf, dH, R,
                                              Wqb, Wkb, W1b, W2b, W3b, Wqrt,
                                              Gbs, Ejb, Rb, Rtb);
  kB<<<dim3(NB * NS), dim3(256), 0, stream>>>(H, W1b, W2b, Wqrt, Gbs,
                                              bf, Ejb, Apbb, BEb, Gb, Ht);
  kQK<<<dim3(NB * NT), dim3(512), 0, stream>>>(Ht, Wqb, Wkb, bq, bk, Sb);
  kSM<<<dim3(NB * NS), dim3(256), 0, stream>>>(Gb, Rb, Rtb, Sb, W3b, Apbb, Wbw);
  kD<<<dim3(NB * NT), dim3(512), 0, stream>>>(Wbw, BEb, Apbb, H, gamma, beta, out);
}

// Round 14
// 142.792 us; speedup vs baseline: 1.1048x; 1.0642x over previous
//
#include <hip/hip_runtime.h>

typedef __attribute__((ext_vector_type(4))) float f32x4;
typedef __attribute__((ext_vector_type(8))) short short8;

constexpr int NB = 4, NS = 256, NT = 64, ND = 128, NR = 32;
constexpr int WFR = 3 * ND + NR;              // 416
constexpr float SCALE = 0.08838834764831845f; // 1/sqrt(128)

__device__ __forceinline__ unsigned short f2bf(float f) {
  unsigned x = __float_as_uint(f);
  return (unsigned short)((x + 0x7FFFu + ((x >> 16) & 1u)) >> 16);
}
__device__ __forceinline__ float bf2f(unsigned short u) {
  return __uint_as_float((unsigned)u << 16);
}

// ---------------- kPrep: fused kP (blocks 0..115) + kA (116..627) +
// kR (628..1651). Block-uniform branches.
__global__ __launch_bounds__(256) void kPrep(
    const float* __restrict__ Wq, const float* __restrict__ Wk,
    const float* __restrict__ Wr, const float* __restrict__ br,
    const float* __restrict__ bq, const float* __restrict__ Wf,
    const float* __restrict__ dH, const float* __restrict__ R,
    unsigned short* __restrict__ Wqb, unsigned short* __restrict__ Wkb,
    unsigned short* __restrict__ W1b, unsigned short* __restrict__ W2b,
    unsigned short* __restrict__ W3b, unsigned short* __restrict__ Wqrt,
    float* __restrict__ Gbias, float* __restrict__ Ej,
    unsigned short* __restrict__ Rb, unsigned short* __restrict__ Rtb) {
  __shared__ __align__(16) char smem[17408];
  const int blk = blockIdx.x, tid = threadIdx.x;
  if (blk < 116) {
    // ---- kP
    if (blk < 64) {
      const int which = blk >> 4;
      const int idx = ((blk & 15) * 256 + tid) * 4;
      const int e = idx >> 7, d = idx & 127;
      float4 v;
      unsigned short* dst;
      if (which == 0)      { v = *(const float4*)&Wq[idx];            dst = Wqb; }
      else if (which == 1) { v = *(const float4*)&Wk[idx];            dst = Wkb; }
      else if (which == 2) { v = *(const float4*)&Wf[e * WFR + d];        dst = W1b; }
      else                 { v = *(const float4*)&Wf[e * WFR + ND + d];   dst = W2b; }
      dst[idx + 0] = f2bf(v.x); dst[idx + 1] = f2bf(v.y);
      dst[idx + 2] = f2bf(v.z); dst[idx + 3] = f2bf(v.w);
    } else if (blk < 68) {
      const int idx = ((blk - 64) * 256 + tid) * 4;
      const int e = idx >> 5, r = idx & 31;
      float4 v = *(const float4*)&Wf[e * WFR + 2 * ND + r];
      W3b[idx + 0] = f2bf(v.x); W3b[idx + 1] = f2bf(v.y);
      W3b[idx + 2] = f2bf(v.z); W3b[idx + 3] = f2bf(v.w);
    } else {
      const int rr = blk - 68;  // 0..47
      float* Vl = (float*)smem;
      float* gbl = Vl + 128;
      if (tid < 128) {
        float v = 0.f;
        if (rr < 32) v = Wr[tid * 32 + rr];
        else if (rr == 32) v = br[tid];
        Vl[tid] = v;
        gbl[tid] = bq[tid] * v;
      }
      __syncthreads();
      if (tid < 128) {
        float acc = 0.f;
        #pragma unroll 8
        for (int h = 0; h < 128; ++h) acc += Wq[h * 128 + tid] * Vl[h];
        Wqrt[rr * 128 + tid] = f2bf(acc * SCALE);
      }
      if (tid == 0) {
        float g = 0.f;
        for (int h = 0; h < 128; ++h) g += gbl[h];
        Gbias[rr] = g * SCALE;
      }
    }
  } else if (blk < 628) {
    // ---- kA: two (b,j) rows per block
    float* ds = (float*)smem;  // [2][128]
    const int half = tid >> 7, d = tid & 127;
    const int bj = (blk - 116) * 2 + half;
    const float* p = dH + (size_t)bj * NT * ND + d;
    float s = 0.f;
    #pragma unroll 8
    for (int t = 0; t < NT; ++t) s += p[t * ND];
    ds[half * 128 + d] = s;
    __syncthreads();
    const float* w4 = Wf + (size_t)d * WFR + 2 * ND + NR;
    float acc = 0.f;
    #pragma unroll 8
    for (int dd = 0; dd < ND; ++dd) acc += ds[half * 128 + dd] * w4[dd];
    Ej[(size_t)bj * ND + d] = acc;
  } else {
    // ---- kR
    unsigned short* rt = (unsigned short*)smem;  // [256][34]
    const int bi = blk - 628;
    const float* src = R + (size_t)bi * 8192;
    #pragma unroll
    for (int it = 0; it < 8; ++it) {
      const int idx = (tid + it * 256) * 4;
      const float4 v = *(const float4*)&src[idx];
      const unsigned short s0 = f2bf(v.x), s1 = f2bf(v.y);
      const unsigned short s2 = f2bf(v.z), s3 = f2bf(v.w);
      unsigned long long p = (unsigned long long)s0 | ((unsigned long long)s1 << 16)
                           | ((unsigned long long)s2 << 32) | ((unsigned long long)s3 << 48);
      *(unsigned long long*)&Rb[(size_t)bi * 8192 + idx] = p;
      const int j = idx >> 5, r = idx & 31;
      *(unsigned*)&rt[j * 34 + r]     = (unsigned)s0 | ((unsigned)s1 << 16);
      *(unsigned*)&rt[j * 34 + r + 2] = (unsigned)s2 | ((unsigned)s3 << 16);
    }
    __syncthreads();
    #pragma unroll
    for (int it = 0; it < 4; ++it) {
      const int flat = (tid + it * 256) * 8;
      const int r = flat >> 8, j0 = flat & 255;
      short8 o;
      #pragma unroll
      for (int u = 0; u < 8; ++u) o[u] = (short)rt[(j0 + u) * 34 + r];
      *(short8*)&Rtb[(size_t)bi * 8192 + flat] = o;
    }
  }
}

__device__ __forceinline__ void gemm_tile(const short8 (&afr)[4][4],
    const unsigned short* __restrict__ Wp, int nt, int l15, int l4,
    f32x4 (&acc)[4]) {
  #pragma unroll
  for (int mt = 0; mt < 4; ++mt) acc[mt] = (f32x4){0.f, 0.f, 0.f, 0.f};
  #pragma unroll
  for (int kt = 0; kt < 4; ++kt) {
    short8 bfr = *(const short8*)(Wp + (16 * nt + l15) * 128 + 32 * kt + 8 * l4);
    #pragma unroll
    for (int mt = 0; mt < 4; ++mt)
      acc[mt] = __builtin_amdgcn_mfma_f32_16x16x32_bf16(afr[mt][kt], bfr, acc[mt], 0, 0, 0);
  }
}

__device__ __forceinline__ void gemm_tile2(const short8 (&afr)[2][4],
    const unsigned short* __restrict__ Wp, int nt, int l15, int l4,
    f32x4 (&acc)[2]) {
  #pragma unroll
  for (int mt = 0; mt < 2; ++mt) acc[mt] = (f32x4){0.f, 0.f, 0.f, 0.f};
  #pragma unroll
  for (int kt = 0; kt < 4; ++kt) {
    short8 bfr = *(const short8*)(Wp + (16 * nt + l15) * 128 + 32 * kt + 8 * l4);
    #pragma unroll
    for (int mt = 0; mt < 2; ++mt)
      acc[mt] = __builtin_amdgcn_mfma_f32_16x16x32_bf16(afr[mt][kt], bfr, acc[mt], 0, 0, 0);
  }
}

// ---------------- kB: per (b,n): Apb, BE, G projections + Ht emission.
// BE: [b][t][j][e]; Apbb: [b][i][t][e]; G: [b][i][t][48]; Ht: [b][t][n][d]
__global__ __launch_bounds__(256) void kB(const float* __restrict__ H,
    const unsigned short* __restrict__ W1b, const unsigned short* __restrict__ W2b,
    const unsigned short* __restrict__ Wqrt, const float* __restrict__ Gbias,
    const float* __restrict__ bf, const float* __restrict__ Ej,
    unsigned short* __restrict__ Apbb, unsigned short* __restrict__ BEb,
    unsigned short* __restrict__ Gb, unsigned short* __restrict__ Ht) {
  __shared__ unsigned short st[2][64 * 136];  // 34,816 B
  const int bn = blockIdx.x, tid = threadIdx.x;
  const int b = bn >> 8, n = bn & 255;
  const int lane = tid & 63, wv = tid >> 6;
  const int l15 = lane & 15, l4 = lane >> 4;
  // A-fragments of H (bf16 on the fly); every wave holds the full 64-row tile
  short8 afr[4][4];
  const float* hb = H + (size_t)bn * (NT * ND);
  #pragma unroll
  for (int mt = 0; mt < 4; ++mt)
    #pragma unroll
    for (int kt = 0; kt < 4; ++kt) {
      const float* p = hb + (16 * mt + l15) * ND + 32 * kt + 8 * l4;
      float4 u0 = *(const float4*)p;
      float4 u1 = *(const float4*)(p + 4);
      short8 f;
      f[0] = (short)f2bf(u0.x); f[1] = (short)f2bf(u0.y);
      f[2] = (short)f2bf(u0.z); f[3] = (short)f2bf(u0.w);
      f[4] = (short)f2bf(u1.x); f[5] = (short)f2bf(u1.y);
      f[6] = (short)f2bf(u1.z); f[7] = (short)f2bf(u1.w);
      afr[mt][kt] = f;
    }
  f32x4 acc[4];
  // passes 0..1 -> LDS buffers (no inter-pass barrier)
  #pragma unroll 1
  for (int pass = 0; pass < 2; ++pass) {
    const unsigned short* W = (pass == 0) ? W1b : W2b;
    unsigned short* buf = st[pass];
    #pragma unroll
    for (int n2 = 0; n2 < 2; ++n2) {
      const int nt = 2 * wv + n2, c = 16 * nt + l15;
      gemm_tile(afr, W, nt, l15, l4, acc);
      const float bias = (pass == 0) ? bf[c] : Ej[(size_t)bn * 128 + c];
      #pragma unroll
      for (int mt = 0; mt < 4; ++mt)
        #pragma unroll
        for (int jr = 0; jr < 4; ++jr)
          buf[(16 * mt + 4 * l4 + jr) * 136 + c] = f2bf(acc[mt][jr] + bias);
    }
  }
  // pass G = H.Wqrt + Gbias (48 cols; waves 0..2) — scalar stores, small
  if (wv < 3) {
    const int nt = wv, c = 16 * nt + l15;
    gemm_tile(afr, Wqrt, nt, l15, l4, acc);
    const float bias = Gbias[c];
    #pragma unroll
    for (int mt = 0; mt < 4; ++mt)
      #pragma unroll
      for (int jr = 0; jr < 4; ++jr) {
        const int tr = 16 * mt + 4 * l4 + jr;
        Gb[(size_t)bn * 3072 + tr * 48 + c] = f2bf(acc[mt][jr] + bias);
      }
  }
  __syncthreads();
  // coalesced stores: 256 B per 16-lane group
  #pragma unroll
  for (int it = 0; it < 4; ++it) {
    const int flat = tid * 8 + it * 2048;
    const int row = flat >> 7, col = flat & 127;  // row = t
    *(short8*)&Apbb[(size_t)bn * 8192 + flat] = *(const short8*)&st[0][row * 136 + col];
    *(short8*)&BEb[((size_t)(b * 64 + row) * 256 + n) * 128 + col] =
        *(const short8*)&st[1][row * 136 + col];
  }
  // Ht emission: restage bf16 H tile (wave 0 holds it all) -> coalesced stores
  __syncthreads();
  if (wv == 0) {
    #pragma unroll
    for (int mt = 0; mt < 4; ++mt)
      #pragma unroll
      for (int kt = 0; kt < 4; ++kt)
        *(short8*)&st[0][(16 * mt + l15) * 136 + 32 * kt + 8 * l4] = afr[mt][kt];
  }
  __syncthreads();
  #pragma unroll
  for (int it = 0; it < 4; ++it) {
    const int flat = tid * 8 + it * 2048;
    const int row = flat >> 7, col = flat & 127;  // row = t
    *(short8*)&Ht[((size_t)(b * 64 + row) * 256 + n) * 128 + col] =
        *(const short8*)&st[0][row * 136 + col];
  }
}

// ---------------- kQK: per (b,t): project q,k in-block (LDS), S = SCALE*q.k^T
// Sb: [b][t][i][j]. 512 thr / 8 waves; wave wv owns i-rows [32wv, 32wv+32).
__global__ __launch_bounds__(512) void kQK(const unsigned short* __restrict__ Ht,
    const unsigned short* __restrict__ Wqb, const unsigned short* __restrict__ Wkb,
    const float* __restrict__ bq, const float* __restrict__ bk,
    unsigned short* __restrict__ Sb) {
  __shared__ unsigned short qs[256 * 136];  // 69,632 B (also reused for S staging)
  __shared__ unsigned short ks[256 * 136];  // 69,632 B
  const int bt = blockIdx.x;
  const int tid = threadIdx.x, lane = tid & 63, wv = tid >> 6;
  const int l15 = lane & 15, l4 = lane >> 4;
  // A-fragments from Ht (already bf16, contiguous per (b,t) slice)
  const unsigned short* hsrc = Ht + (size_t)bt * (256 * 128);
  short8 afr[2][4];
  #pragma unroll
  for (int mt = 0; mt < 2; ++mt)
    #pragma unroll
    for (int kt = 0; kt < 4; ++kt) {
      const int n = 32 * wv + 16 * mt + l15;
      afr[mt][kt] = *(const short8*)(hsrc + n * 128 + 32 * kt + 8 * l4);
    }
  // q and k projections -> LDS
  f32x4 acc[2];
  #pragma unroll 1
  for (int pass = 0; pass < 2; ++pass) {
    const unsigned short* W = (pass == 0) ? Wqb : Wkb;
    const float* bp = (pass == 0) ? bq : bk;
    unsigned short* dst = (pass == 0) ? qs : ks;
    #pragma unroll
    for (int nt = 0; nt < 8; ++nt) {
      gemm_tile2(afr, W, nt, l15, l4, acc);
      const int c = 16 * nt + l15;
      const float bias = bp[c];
      #pragma unroll
      for (int mt = 0; mt < 2; ++mt)
        #pragma unroll
        for (int jr = 0; jr < 4; ++jr)
          dst[(32 * wv + 16 * mt + 4 * l4 + jr) * 136 + c] = f2bf(acc[mt][jr] + bias);
    }
  }
  __syncthreads();
  // own q A-fragments from LDS (only this wave wrote/reads these rows)
  short8 qa[2][4];
  #pragma unroll
  for (int mt = 0; mt < 2; ++mt)
    #pragma unroll
    for (int kt = 0; kt < 4; ++kt)
      qa[mt][kt] = *(const short8*)&qs[(32 * wv + 16 * mt + l15) * 136 + 32 * kt + 8 * l4];
  // QK^T in two j-halves; stage into wave-private region of qs, coalesced store
  unsigned short* buf = qs + wv * (32 * 136);
  #pragma unroll 1
  for (int jh = 0; jh < 2; ++jh) {
    f32x4 sacc[2][8];
    #pragma unroll
    for (int mi = 0; mi < 2; ++mi)
      #pragma unroll
      for (int ntj = 0; ntj < 8; ++ntj) sacc[mi][ntj] = (f32x4){0.f, 0.f, 0.f, 0.f};
    #pragma unroll
    for (int kt = 0; kt < 4; ++kt) {
      short8 bb[8];
      #pragma unroll
      for (int ntj = 0; ntj < 8; ++ntj)
        bb[ntj] = *(const short8*)&ks[(16 * (8 * jh + ntj) + l15) * 136 + 32 * kt + 8 * l4];
      #pragma unroll
      for (int mi = 0; mi < 2; ++mi)
        #pragma unroll
        for (int ntj = 0; ntj < 8; ++ntj)
          sacc[mi][ntj] = __builtin_amdgcn_mfma_f32_16x16x32_bf16(qa[mi][kt], bb[ntj], sacc[mi][ntj], 0, 0, 0);
    }
    #pragma unroll
    for (int mi = 0; mi < 2; ++mi)
      #pragma unroll
      for (int ntj = 0; ntj < 8; ++ntj)
        #pragma unroll
        for (int jr = 0; jr < 4; ++jr)
          buf[(16 * mi + 4 * l4 + jr) * 136 + 16 * ntj + l15] =
              f2bf(sacc[mi][ntj][jr] * SCALE);
    #pragma unroll
    for (int it = 0; it < 8; ++it) {
      const int flat = lane * 8 + it * 512;
      const int row = flat >> 7, col = flat & 127;
      *(short8*)&Sb[((size_t)bt * 256 + 32 * wv + row) * 256 + 128 * jh + col] =
          *(const short8*)&buf[row * 136 + col];
    }
  }
}

// ---------------- kSM: per (b,i): scores+softmax+mask+wsum, w->Wbw,
//                  M=w.R, T2=M.W3^T, zacc = Apbb*wsum + T2 -> Zt[b][t][i][e]
__global__ __launch_bounds__(256) void kSM(
    const unsigned short* __restrict__ Gb, const unsigned short* __restrict__ Rb,
    const unsigned short* __restrict__ Rtb, const unsigned short* __restrict__ Sb,
    const unsigned short* __restrict__ W3b, const unsigned short* __restrict__ Apbb,
    unsigned short* __restrict__ Zt, unsigned short* __restrict__ Wbw) {
  __shared__ unsigned short wl[64 * 264];
  __shared__ unsigned short Ml[4][16 * 40];
  __shared__ float wred[4][64];
  __shared__ float wsl[64];
  const int bi = blockIdx.x, b = bi >> 8, i = bi & 255;
  const int tid = threadIdx.x, lane = tid & 63, wv = tid >> 6;
  const int l15 = lane & 15, l4 = lane >> 4;
  const f32x4 zz = (f32x4){0.f, 0.f, 0.f, 0.f};

  // stage S tile: wl[t][j] <- Sb[b][t][i][j]  (512 B contiguous per t-row)
  #pragma unroll
  for (int it = 0; it < 8; ++it) {
    const int flat = tid * 8 + it * 2048;
    const int t = flat >> 8, col = flat & 255;
    *(short8*)&wl[t * 264 + col] =
        *(const short8*)&Sb[(((size_t)b * 64 + t) * 256 + i) * 256 + col];
  }

  // P = G . R^T  (K=32)
  short8 ga[4];
  #pragma unroll
  for (int mt = 0; mt < 4; ++mt)
    ga[mt] = *(const short8*)(Gb + ((size_t)bi * 64 + 16 * mt + l15) * 48 + 8 * l4);
  f32x4 acc[4][4];
  #pragma unroll
  for (int nt = 0; nt < 4; ++nt) {
    const int j = 64 * wv + 16 * nt + l15;
    short8 rb = *(const short8*)(Rb + ((size_t)bi * 256 + j) * 32 + 8 * l4);
    #pragma unroll
    for (int mt = 0; mt < 4; ++mt)
      acc[mt][nt] = __builtin_amdgcn_mfma_f32_16x16x32_bf16(ga[mt], rb, zz, 0, 0, 0);
  }
  float qbr[4][4];
  #pragma unroll
  for (int mt = 0; mt < 4; ++mt)
    #pragma unroll
    for (int jr = 0; jr < 4; ++jr)
      qbr[mt][jr] = bf2f(Gb[((size_t)bi * 64 + 16 * mt + 4 * l4 + jr) * 48 + 32]);

  __syncthreads();  // S staged

  // += S + qbr
  #pragma unroll
  for (int mt = 0; mt < 4; ++mt)
    #pragma unroll
    for (int nt = 0; nt < 4; ++nt)
      #pragma unroll
      for (int jr = 0; jr < 4; ++jr)
        acc[mt][nt][jr] += bf2f(wl[(16 * mt + 4 * l4 + jr) * 264 + 64 * wv + 16 * nt + l15])
                         + qbr[mt][jr];

  // softmax over t per column j, diag mask
  #pragma unroll
  for (int nt = 0; nt < 4; ++nt) {
    float mx = -1e30f;
    #pragma unroll
    for (int mt = 0; mt < 4; ++mt)
      #pragma unroll
      for (int jr = 0; jr < 4; ++jr) mx = fmaxf(mx, acc[mt][nt][jr]);
    mx = fmaxf(mx, __shfl_xor(mx, 16));
    mx = fmaxf(mx, __shfl_xor(mx, 32));
    float sm = 0.f;
    #pragma unroll
    for (int mt = 0; mt < 4; ++mt)
      #pragma unroll
      for (int jr = 0; jr < 4; ++jr) {
        const float e = __expf(acc[mt][nt][jr] - mx);
        acc[mt][nt][jr] = e;
        sm += e;
      }
    sm += __shfl_xor(sm, 16);
    sm += __shfl_xor(sm, 32);
    const int j = 64 * wv + 16 * nt + l15;
    const float inv = (j == i) ? 0.f : 1.f / sm;
    #pragma unroll
    for (int mt = 0; mt < 4; ++mt)
      #pragma unroll
      for (int jr = 0; jr < 4; ++jr) acc[mt][nt][jr] *= inv;
  }

  // wsum partials
  float part[4][4];
  #pragma unroll
  for (int mt = 0; mt < 4; ++mt)
    #pragma unroll
    for (int jr = 0; jr < 4; ++jr) {
      float s = 0.f;
      #pragma unroll
      for (int nt = 0; nt < 4; ++nt) s += acc[mt][nt][jr];
      part[mt][jr] = s;
    }
  #pragma unroll
  for (int m = 1; m < 16; m <<= 1)
    #pragma unroll
    for (int mt = 0; mt < 4; ++mt)
      #pragma unroll
      for (int jr = 0; jr < 4; ++jr) part[mt][jr] += __shfl_xor(part[mt][jr], m);
  if (l15 == 0) {
    #pragma unroll
    for (int mt = 0; mt < 4; ++mt)
      #pragma unroll
      for (int jr = 0; jr < 4; ++jr) wred[wv][16 * mt + 4 * l4 + jr] = part[mt][jr];
  }

  // w -> wl (own elements; overwrites staged S values at same addresses)
  #pragma unroll
  for (int mt = 0; mt < 4; ++mt)
    #pragma unroll
    for (int nt = 0; nt < 4; ++nt)
      #pragma unroll
      for (int jr = 0; jr < 4; ++jr)
        wl[(16 * mt + 4 * l4 + jr) * 264 + 64 * wv + 16 * nt + l15] =
            f2bf(acc[mt][nt][jr]);

  __syncthreads();  // w staged + wred complete

  if (tid < 64) wsl[tid] = wred[0][tid] + wred[1][tid] + wred[2][tid] + wred[3][tid];

  // coalesced Wbw store  Wbw[b][t][i][j]
  #pragma unroll
  for (int it = 0; it < 8; ++it) {
    const int flat = tid * 8 + it * 2048;
    const int t = flat >> 8, j = flat & 255;
    *(short8*)&Wbw[(((size_t)(b * 64 + t)) * 256 + i) * 256 + j] =
        *(const short8*)&wl[t * 264 + j];
  }

  // M = w.R : wave wv owns t-rows [16wv, 16wv+16)
  f32x4 mac[2];
  mac[0] = zz; mac[1] = zz;
  #pragma unroll
  for (int kt = 0; kt < 8; ++kt) {
    short8 a = *(const short8*)&wl[(16 * wv + l15) * 264 + 32 * kt + 8 * l4];
    #pragma unroll
    for (int nt = 0; nt < 2; ++nt) {
      short8 bb = *(const short8*)(Rtb + ((size_t)bi * 32 + 16 * nt + l15) * 256 + 32 * kt + 8 * l4);
      mac[nt] = __builtin_amdgcn_mfma_f32_16x16x32_bf16(a, bb, mac[nt], 0, 0, 0);
    }
  }
  #pragma unroll
  for (int nt = 0; nt < 2; ++nt)
    #pragma unroll
    for (int jr = 0; jr < 4; ++jr)
      Ml[wv][(4 * l4 + jr) * 40 + 16 * nt + l15] = f2bf(mac[nt][jr]);
  asm volatile("s_waitcnt lgkmcnt(0)" ::: "memory");
  // T2 = M . W3^T  (K=32)
  short8 a2 = *(const short8*)&Ml[wv][l15 * 40 + 8 * l4];
  f32x4 tac[8];
  #pragma unroll
  for (int nt = 0; nt < 8; ++nt) {
    short8 w3 = *(const short8*)(W3b + (16 * nt + l15) * 32 + 8 * l4);
    tac[nt] = __builtin_amdgcn_mfma_f32_16x16x32_bf16(a2, w3, zz, 0, 0, 0);
  }
  __syncthreads();  // all wl reads (M-step) done

  // stage Apbb tile [64][128] -> wl as [64][136]
  const size_t abase = (size_t)bi * 8192;
  #pragma unroll
  for (int it = 0; it < 4; ++it) {
    const int flat = tid * 8 + it * 2048;
    const int row = flat >> 7, col = flat & 127;
    *(short8*)&wl[row * 136 + col] = *(const short8*)&Apbb[abase + flat];
  }
  __syncthreads();
  // zacc = Apbb * wsum + T2 (in LDS, own elements)
  #pragma unroll
  for (int jr = 0; jr < 4; ++jr) {
    const int t = 16 * wv + 4 * l4 + jr;
    const float ws = wsl[t];
    #pragma unroll
    for (int nt = 0; nt < 8; ++nt) {
      const int e = 16 * nt + l15;
      const int off = t * 136 + e;
      wl[off] = f2bf(bf2f(wl[off]) * ws + tac[nt][jr]);
    }
  }
  __syncthreads();
  // store zacc to Zt[b][t][i][e] (256 B chunks, t-scattered)
  #pragma unroll
  for (int it = 0; it < 4; ++it) {
    const int flat = tid * 8 + it * 2048;
    const int row = flat >> 7, col = flat & 127;  // row = t
    *(short8*)&Zt[((size_t)(b * 64 + row) * 256 + i) * 128 + col] =
        *(const short8*)&wl[row * 136 + col];
  }
}

// ---------------- kD: per (b,t): out = LN(Ht + Zt + w.BE); all tiles t-major
__global__ __launch_bounds__(512) void kD(const unsigned short* __restrict__ Wb,
    const unsigned short* __restrict__ BEb, const unsigned short* __restrict__ Zt,
    const unsigned short* __restrict__ Ht, const float* __restrict__ gamma,
    const float* __restrict__ beta, float* __restrict__ out) {
  __shared__ unsigned short Bl[128 * 264];  // 67,584 B; reused as [256][132]
  const int bt = blockIdx.x;
  const int b = bt >> 6, t = bt & 63;
  const int tid = threadIdx.x, lane = tid & 63, wv = tid >> 6;
  const int l15 = lane & 15, l4 = lane >> 4;
  // stage BE[t][j][e] -> Bl[e][j]  (transposed, pad 264); global read contiguous
  {
    const int j = tid >> 1, eh = (tid & 1) * 64;
    const unsigned short* src = BEb + (size_t)bt * (256 * 128) + j * 128 + eh;
    #pragma unroll
    for (int eg = 0; eg < 8; ++eg) {
      short8 v = *(const short8*)(src + 8 * eg);
      #pragma unroll
      for (int u = 0; u < 8; ++u)
        Bl[(eh + 8 * eg + u) * 264 + j] = (unsigned short)v[u];
    }
  }
  __syncthreads();
  f32x4 acc[2][8];
  #pragma unroll
  for (int m2 = 0; m2 < 2; ++m2)
    #pragma unroll
    for (int nt = 0; nt < 8; ++nt) acc[m2][nt] = (f32x4){0.f, 0.f, 0.f, 0.f};
  #pragma unroll
  for (int kt = 0; kt < 8; ++kt) {
    short8 a[2];
    #pragma unroll
    for (int m2 = 0; m2 < 2; ++m2) {
      const int i = 32 * wv + 16 * m2 + l15;
      a[m2] = *(const short8*)(Wb + ((size_t)(b * 64 + t) * 256 + i) * 256 + 32 * kt + 8 * l4);
    }
    #pragma unroll
    for (int nt = 0; nt < 8; ++nt) {
      short8 bb = *(const short8*)(&Bl[(16 * nt + l15) * 264 + 32 * kt + 8 * l4]);
      #pragma unroll
      for (int m2 = 0; m2 < 2; ++m2)
        acc[m2][nt] = __builtin_amdgcn_mfma_f32_16x16x32_bf16(a[m2], bb, acc[m2][nt], 0, 0, 0);
    }
  }
  // ---- epilogue: acc += Zt then += Ht (staged via LDS, contiguous reads)
  unsigned short* Zl = Bl;  // reuse as [256][132]
  #pragma unroll 1
  for (int src = 0; src < 2; ++src) {
    const unsigned short* gsrc = (src == 0) ? Zt : Ht;
    __syncthreads();  // previous Bl/Zl reads complete
    #pragma unroll
    for (int it = 0; it < 8; ++it) {
      const int flat = tid * 8 + it * 4096;
      const int row = flat >> 7, col = flat & 127;  // row = i
      *(short8*)&Zl[row * 132 + col] =
          *(const short8*)&gsrc[((size_t)bt * 256 + row) * 128 + col];
    }
    __syncthreads();
    #pragma unroll
    for (int m2 = 0; m2 < 2; ++m2)
      #pragma unroll
      for (int jr = 0; jr < 4; ++jr) {
        const int i = 32 * wv + 16 * m2 + 4 * l4 + jr;
        #pragma unroll
        for (int nt = 0; nt < 8; ++nt)
          acc[m2][nt][jr] += bf2f(Zl[i * 132 + 16 * nt + l15]);
      }
  }
  // LayerNorm over e, store
  float gam[8], bet[8];
  #pragma unroll
  for (int nt = 0; nt < 8; ++nt) {
    const int e = 16 * nt + l15;
    gam[nt] = gamma[e];
    bet[nt] = beta[e];
  }
  #pragma unroll
  for (int m2 = 0; m2 < 2; ++m2)
    #pragma unroll
    for (int jr = 0; jr < 4; ++jr) {
      const int i = 32 * wv + 16 * m2 + 4 * l4 + jr;
      const size_t base = ((size_t)(b * 256 + i) * 64 + t) * 128;
      float sm = 0.f, sq = 0.f;
      #pragma unroll
      for (int nt = 0; nt < 8; ++nt) {
        const float v = acc[m2][nt][jr];
        sm += v;
        sq += v * v;
      }
      #pragma unroll
      for (int m = 1; m < 16; m <<= 1) {
        sm += __shfl_xor(sm, m);
        sq += __shfl_xor(sq, m);
      }
      const float mu = sm * (1.f / 128.f);
      const float inv = rsqrtf(sq * (1.f / 128.f) - mu * mu + 1e-5f);
      #pragma unroll
      for (int nt = 0; nt < 8; ++nt)
        out[base + 16 * nt + l15] = (acc[m2][nt][jr] - mu) * inv * gam[nt] + bet[nt];
    }
}

extern "C" void kernel_launch(void* const* d_in, const int* in_sizes, int n_in,
                              void* d_out, int out_size, void* d_ws, size_t ws_size,
                              hipStream_t stream) {
  (void)in_sizes; (void)n_in; (void)out_size; (void)ws_size;
  const float* H     = (const float*)d_in[0];
  const float* R     = (const float*)d_in[1];
  const float* dH    = (const float*)d_in[2];
  const float* Wq    = (const float*)d_in[3];
  const float* bq    = (const float*)d_in[4];
  const float* Wk    = (const float*)d_in[5];
  const float* bk    = (const float*)d_in[6];
  const float* Wr    = (const float*)d_in[7];
  const float* br    = (const float*)d_in[8];
  const float* Wf    = (const float*)d_in[9];
  const float* bf    = (const float*)d_in[10];
  const float* gamma = (const float*)d_in[11];
  const float* beta  = (const float*)d_in[12];
  float* out = (float*)d_out;
  char* w = (char*)d_ws;

  unsigned short* Wbw  = (unsigned short*)(w + 0);           // 33,554,432
  unsigned short* Sb   = (unsigned short*)(w + 33554432);    // 33,554,432
  unsigned short* Apbb = (unsigned short*)(w + 67108864);    // 16,777,216
  unsigned short* BEb  = (unsigned short*)(w + 83886080);    // 16,777,216
  unsigned short* Gb   = (unsigned short*)(w + 100663296);   //  6,291,456
  unsigned short* Rb   = (unsigned short*)(w + 106954752);   // 16,777,216
  unsigned short* Rtb  = (unsigned short*)(w + 123731968);   // 16,777,216
  float*          Ejb  = (float*)(w + 140509184);            //    524,288
  unsigned short* Wqb  = (unsigned short*)(w + 141033472);   //     32,768
  unsigned short* Wkb  = (unsigned short*)(w + 141066240);
  unsigned short* W1b  = (unsigned short*)(w + 141099008);
  unsigned short* W2b  = (unsigned short*)(w + 141131776);
  unsigned short* W3b  = (unsigned short*)(w + 141164544);   //      8,192
  unsigned short* Wqrt = (unsigned short*)(w + 141172736);   //     12,288
  float*          Gbs  = (float*)(w + 141185024);            //        192
  unsigned short* Ht   = (unsigned short*)(w + 141185280);   // 16,777,216
  unsigned short* Zt   = (unsigned short*)(w + 157962496);   // 16,777,216

  kPrep<<<dim3(1652), dim3(256), 0, stream>>>(Wq, Wk, Wr, br, bq, Wf, dH, R,
                                              Wqb, Wkb, W1b, W2b, W3b, Wqrt,
                                              Gbs, Ejb, Rb, Rtb);
  kB<<<dim3(NB * NS), dim3(256), 0, stream>>>(H, W1b, W2b, Wqrt, Gbs,
                                              bf, Ejb, Apbb, BEb, Gb, Ht);
  kQK<<<dim3(NB * NT), dim3(512), 0, stream>>>(Ht, Wqb, Wkb, bq, bk, Sb);
  kSM<<<dim3(NB * NS), dim3(256), 0, stream>>>(Gb, Rb, Rtb, Sb, W3b, Apbb, Zt, Wbw);
  kD<<<dim3(NB * NT), dim3(512), 0, stream>>>(Wbw, BEb, Zt, Ht, gamma, beta, out);
}